// Round 2
// baseline (10248.442 us; speedup 1.0000x reference)
//
#include <hip/hip_runtime.h>
#include <hip/hip_bf16.h>

#define TT   1024    // time steps (32x32 raster)
#define KPAD 1088    // 64 (x padded from 48) + 512 (prev2) + 512 (h)

typedef __attribute__((ext_vector_type(8))) short short8;
typedef __attribute__((ext_vector_type(4))) float floatx4;
using bf16 = __hip_bfloat16;

__device__ __forceinline__ float fsig(float x) { return 1.f / (1.f + __expf(-x)); }
__device__ __forceinline__ float ftanh(float x) {
    float e = __expf(2.f * fminf(fmaxf(x, -15.f), 15.f));
    return (e - 1.f) / (e + 1.f);
}

// Build combined bf16 weight matrix Wc[row][k], k: [0,48)=W_ih x-part, [48,64)=0,
// [64,576)=W_ih prev2-part, [576,1088)=W_hh. Also bias = b_ih + b_hh (fp32).
__global__ void prep_wb(const float* __restrict__ Wih, const float* __restrict__ Whh,
                        const float* __restrict__ bih, const float* __restrict__ bhh,
                        bf16* __restrict__ Wc, float* __restrict__ bias) {
    int idx = blockIdx.x * 256 + threadIdx.x;
    int total = 2048 * KPAD;
    if (idx < total) {
        int row = idx / KPAD;
        int k = idx - row * KPAD;
        float v = 0.f;
        if (k < 48)       v = Wih[row * 560 + k];
        else if (k < 64)  v = 0.f;
        else if (k < 576) v = Wih[row * 560 + 48 + (k - 64)];
        else              v = Whh[row * 512 + (k - 576)];
        Wc[idx] = __float2bfloat16(v);
    }
    if (idx < 2048) bias[idx] = bih[idx] + bhh[idx];
}

// Extract patches: xs[t][b][kk] (kk = c*16 + py*4 + px, padded 48->64 with zeros), bf16.
__global__ void prep_x(const float* __restrict__ batch, bf16* __restrict__ xs) {
    int idx = blockIdx.x * 256 + threadIdx.x;   // exactly 1024*64*64 threads
    int kk = idx & 63;
    int b  = (idx >> 6) & 63;
    int t  = idx >> 12;
    float v = 0.f;
    if (kk < 48) {
        int c = kk >> 4, py = (kk >> 2) & 3, px = kk & 3;
        int i = t >> 5, j = t & 31;
        v = batch[((b * 3 + c) * 128 + (i * 4 + py)) * 128 + (j * 4 + px)];
    }
    xs[idx] = __float2bfloat16(v);
}

// Persistent 2D-LSTM. 128 WGs = 4 batch-groups (16 batches each, independent) x
// 32 cell-chunk WGs (16 cells each). Wave w computes gate w for its WG's 16 cells
// (rows w*512 + wgc*16 + [0,16)) over all 16 batches via mfma_f32_16x16x32_bf16.
// Weights stay in VGPRs for the whole kernel (34 short8 frags/wave).
// Per-group sync: monotonic atomic counter (device scope, cross-XCD safe).
__launch_bounds__(256, 1)
__global__ void lstm_persist(const bf16* __restrict__ Wc, const float* __restrict__ bias,
                             const bf16* __restrict__ xs, bf16* __restrict__ ring,
                             float* __restrict__ out, unsigned* __restrict__ barctr)
{
    __shared__ float gsm[4][16][17];   // [gate][batch-in-16][cell-in-16] (+pad)

    const int wg   = blockIdx.x;
    const int bg   = wg >> 5;          // batch group 0..3
    const int wgc  = wg & 31;          // cell chunk 0..31
    const int tid  = threadIdx.x;
    const int w    = tid >> 6;         // wave id == gate id 0..3
    const int lane = tid & 63;
    const int nrow = lane & 15;        // B: row-in-tile (cell j); A: m (batch)
    const int quad = lane >> 4;

    // ---- weights -> registers (one N-tile per wave, K=1088 = 34 frags) ----
    const int grow = w * 512 + wgc * 16 + nrow;     // global gate row
    short8 wf[34];
    {
        const short* wsrc = (const short*)Wc + (size_t)grow * KPAD + quad * 8;
        #pragma unroll
        for (int i = 0; i < 34; ++i) wf[i] = *(const short8*)(wsrc + i * 32);
    }
    const float bias_r = bias[grow];

    const int gb = bg * 16 + nrow;     // global batch for A frags

    // cell-phase mapping: thread -> (batch-in-16, cell-in-16); c-state in register
    const int cm  = tid >> 4, cj = tid & 15;
    const int gcb = bg * 16 + cm;      // global batch
    const int gn  = wgc * 16 + cj;     // global cell
    float creg = 0.f;
    float* outp = out + (size_t)gcb * TT * 512 + gn;
    unsigned* ctr = barctr + bg * 32;  // 128 B apart per group

    for (int t = 0; t < TT; ++t) {
        // ---- A fragments: x (K 0..64), prev2 = h(t-32) (64..576), h(t-1) (576..1088)
        const short* xrow  = (const short*)xs   + ((size_t)t * 64 + gb) * 64 + quad * 8;
        const short* p2row = (const short*)ring + ((size_t)(t & 63) * 64 + gb) * 512 + quad * 8;
        const short* p1row = (const short*)ring + ((size_t)((t + 31) & 63) * 64 + gb) * 512 + quad * 8;

        short8 xa0 = *(const short8*)(xrow);
        short8 xa1 = *(const short8*)(xrow + 32);
        short8 p2f[16], hf[16];
        #pragma unroll
        for (int i = 0; i < 16; ++i) p2f[i] = *(const short8*)(p2row + i * 32);
        #pragma unroll
        for (int i = 0; i < 16; ++i) hf[i]  = *(const short8*)(p1row + i * 32);

        // ---- 34 MFMAs, 4 interleaved accumulators (break the acc dep chain)
        floatx4 acc[4];
        #pragma unroll
        for (int r = 0; r < 4; ++r) acc[r] = (floatx4){0.f, 0.f, 0.f, 0.f};
        acc[0] = __builtin_amdgcn_mfma_f32_16x16x32_bf16(xa0, wf[0], acc[0], 0, 0, 0);
        acc[1] = __builtin_amdgcn_mfma_f32_16x16x32_bf16(xa1, wf[1], acc[1], 0, 0, 0);
        #pragma unroll
        for (int i = 0; i < 16; ++i)
            acc[(2 + i) & 3] = __builtin_amdgcn_mfma_f32_16x16x32_bf16(p2f[i], wf[2 + i], acc[(2 + i) & 3], 0, 0, 0);
        #pragma unroll
        for (int i = 0; i < 16; ++i)
            acc[(18 + i) & 3] = __builtin_amdgcn_mfma_f32_16x16x32_bf16(hf[i], wf[18 + i], acc[(18 + i) & 3], 0, 0, 0);
        floatx4 s = acc[0] + acc[1] + acc[2] + acc[3];

        // D layout: lane holds D[m = quad*4 + r][n = nrow]; m = batch-in-16
        #pragma unroll
        for (int r = 0; r < 4; ++r) gsm[w][quad * 4 + r][nrow] = s[r] + bias_r;
        __syncthreads();

        // ---- LSTM cell (c-state in register)
        float gi = gsm[0][cm][cj], gf = gsm[1][cm][cj];
        float gg = gsm[2][cm][cj], go = gsm[3][cm][cj];
        float cn = fsig(gf) * creg + fsig(gi) * ftanh(gg);
        float h  = fsig(go) * ftanh(cn);
        creg = cn;
        ring[((size_t)((t + 32) & 63) * 64 + gcb) * 512 + gn] = __float2bfloat16(h);
        outp[(size_t)t * 512] = h;   // out is (B, T, NC) flat
        __syncthreads();             // all waves' stores drained to L2 (waitcnt at barrier)

        // ---- per-group barrier: monotonic counter, no reset races
        if (t + 1 < TT) {
            if (tid == 0) {
                __threadfence();  // belt & braces; RELEASE below does agent-scope writeback
                __hip_atomic_fetch_add(ctr, 1u, __ATOMIC_RELEASE, __HIP_MEMORY_SCOPE_AGENT);
                const unsigned tgt = 32u * (unsigned)(t + 1);
                while (__hip_atomic_load(ctr, __ATOMIC_ACQUIRE, __HIP_MEMORY_SCOPE_AGENT) < tgt) {}
            }
            __syncthreads();
        }
    }
}

extern "C" void kernel_launch(void* const* d_in, const int* in_sizes, int n_in,
                              void* d_out, int out_size, void* d_ws, size_t ws_size,
                              hipStream_t stream) {
    const float* batch = (const float*)d_in[0];
    const float* Wih   = (const float*)d_in[1];
    const float* Whh   = (const float*)d_in[2];
    const float* bih   = (const float*)d_in[3];
    const float* bhh   = (const float*)d_in[4];
    float* out = (float*)d_out;

    char* p = (char*)d_ws;
    bf16*  Wc     = (bf16*)p;     p += (size_t)2048 * KPAD * 2;          // 4,456,448
    float* bias   = (float*)p;    p += (size_t)2048 * 4;                 // 8,192
    bf16*  xs     = (bf16*)p;     p += (size_t)TT * 64 * 64 * 2;         // 8,388,608
    bf16*  ring   = (bf16*)p;     p += (size_t)64 * 64 * 512 * 2;        // 4,194,304
    unsigned* bar = (unsigned*)p; p += 512;                              // 4 groups x 128B

    // zero ring slots 0..31 (prev2 for t<32, h(-1) at slot 31) and barrier counters
    hipMemsetAsync(ring, 0, (size_t)32 * 64 * 512 * 2, stream);
    hipMemsetAsync(bar, 0, 512, stream);

    prep_wb<<<(2048 * KPAD + 255) / 256, 256, 0, stream>>>(Wih, Whh, bih, bhh, Wc, bias);
    prep_x<<<(TT * 64 * 64) / 256, 256, 0, stream>>>(batch, xs);

    lstm_persist<<<128, 256, 0, stream>>>(Wc, bias, xs, ring, out, bar);
}

// Round 3
// 4732.205 us; speedup vs baseline: 2.1657x; 2.1657x over previous
//
#include <hip/hip_runtime.h>
#include <hip/hip_bf16.h>

#define TT   1024    // time steps (32x32 raster)
#define KPAD 1088    // 64 (x padded from 48) + 512 (prev2) + 512 (h)
#define LSTR 520     // LDS stage row stride in shorts (512 + 8: 16B-aligned, 2-way banks)

typedef __attribute__((ext_vector_type(8))) short short8;
typedef __attribute__((ext_vector_type(4))) float floatx4;
using bf16 = __hip_bfloat16;

__device__ __forceinline__ float fsig(float x) { return 1.f / (1.f + __expf(-x)); }
__device__ __forceinline__ float ftanh(float x) {
    float e = __expf(2.f * fminf(fmaxf(x, -15.f), 15.f));
    return (e - 1.f) / (e + 1.f);
}

// 16-byte read via two 8B relaxed agent-scope atomic loads: per-access cache
// bypass (sc-flagged), reads the device coherence point. No buffer_inv/wbl2.
__device__ __forceinline__ short8 bypass_load16(const short* p) {
    union { unsigned long long u[2]; short8 v; } r;
    r.u[0] = __hip_atomic_load((const unsigned long long*)p,     __ATOMIC_RELAXED, __HIP_MEMORY_SCOPE_AGENT);
    r.u[1] = __hip_atomic_load((const unsigned long long*)p + 1, __ATOMIC_RELAXED, __HIP_MEMORY_SCOPE_AGENT);
    return r.v;
}

// Build combined bf16 weight matrix Wc[row][k], k: [0,48)=W_ih x-part, [48,64)=0,
// [64,576)=W_ih prev2-part, [576,1088)=W_hh. Also bias = b_ih + b_hh (fp32).
__global__ void prep_wb(const float* __restrict__ Wih, const float* __restrict__ Whh,
                        const float* __restrict__ bih, const float* __restrict__ bhh,
                        bf16* __restrict__ Wc, float* __restrict__ bias) {
    int idx = blockIdx.x * 256 + threadIdx.x;
    int total = 2048 * KPAD;
    if (idx < total) {
        int row = idx / KPAD;
        int k = idx - row * KPAD;
        float v = 0.f;
        if (k < 48)       v = Wih[row * 560 + k];
        else if (k < 64)  v = 0.f;
        else if (k < 576) v = Wih[row * 560 + 48 + (k - 64)];
        else              v = Whh[row * 512 + (k - 576)];
        Wc[idx] = __float2bfloat16(v);
    }
    if (idx < 2048) bias[idx] = bih[idx] + bhh[idx];
}

// Extract patches: xs[t][b][kk] (kk = c*16 + py*4 + px, padded 48->64 with zeros), bf16.
__global__ void prep_x(const float* __restrict__ batch, bf16* __restrict__ xs) {
    int idx = blockIdx.x * 256 + threadIdx.x;   // exactly 1024*64*64 threads
    int kk = idx & 63;
    int b  = (idx >> 6) & 63;
    int t  = idx >> 12;
    float v = 0.f;
    if (kk < 48) {
        int c = kk >> 4, py = (kk >> 2) & 3, px = kk & 3;
        int i = t >> 5, j = t & 31;
        v = batch[((b * 3 + c) * 128 + (i * 4 + py)) * 128 + (j * 4 + px)];
    }
    xs[idx] = __float2bfloat16(v);
}

// Persistent 2D-LSTM. 128 WGs = 4 independent batch-groups x 32 cell-chunk WGs.
// Wave w = gate w for the WG's 16 cells over 16 batches (mfma 16x16x32 bf16).
// Weights pinned in VGPRs (34 short8 frags). Cross-WG h exchange: relaxed
// agent-scope bypass atomics + monotonic counter barrier (no cache-wide ops).
__launch_bounds__(256, 1)
__global__ void lstm_persist(const bf16* __restrict__ Wc, const float* __restrict__ bias,
                             const bf16* __restrict__ xs, bf16* __restrict__ ring,
                             float* __restrict__ out, unsigned* __restrict__ barctr)
{
    __shared__ float gsm[4][16][17];       // [gate][batch-in-16][cell-in-16]
    __shared__ short p2buf[16 * LSTR];     // staged prev2 slot (dedup across 4 waves)
    __shared__ short hbuf[16 * LSTR];      // staged h(t-1) slot

    const int wg   = blockIdx.x;
    const int bg   = wg >> 5;          // batch group 0..3
    const int wgc  = wg & 31;          // cell chunk 0..31
    const int tid  = threadIdx.x;
    const int w    = tid >> 6;         // wave id == gate id 0..3
    const int lane = tid & 63;
    const int mrow = lane & 15;        // A: batch-in-16; B/D: cell-in-16
    const int quad = lane >> 4;

    // ---- weights -> VGPRs, pinned so they can't be rematerialized ----
    const int grow = w * 512 + wgc * 16 + mrow;     // global gate row
    short8 wf[34];
    {
        const short* wsrc = (const short*)Wc + (size_t)grow * KPAD + quad * 8;
        #pragma unroll
        for (int i = 0; i < 34; ++i) wf[i] = *(const short8*)(wsrc + i * 32);
        #pragma unroll
        for (int i = 0; i < 34; ++i) { asm volatile("" : "+v"(wf[i])); }
    }
    const float bias_r = bias[grow];

    // staging roles: lane -> (batch sb, 8-cell chunk sq); wave w stages frags 4w..4w+3
    const int sb = lane & 15;
    const int sq = lane >> 4;

    // cell phase: tid<128, thread -> (batch cm, cell pair cj2); c-state in regs
    const int cm = tid >> 3, cj2 = tid & 7;
    const int gcb = bg * 16 + cm;
    const int gn  = wgc * 16 + cj2 * 2;
    float c0 = 0.f, c1 = 0.f;
    unsigned* ctr = barctr + bg * 32;  // one cacheline per group

    for (int t = 0; t < TT; ++t) {
        // ---- stage prev2 = h(t-32) into LDS (ready since step t-32; no wait) ----
        {
            const short* base = (const short*)ring + ((size_t)(t & 63) * 64 + bg * 16 + sb) * 512;
            #pragma unroll
            for (int f = 0; f < 4; ++f) {
                int frag = w * 4 + f;
                *(short8*)&p2buf[sb * LSTR + frag * 32 + sq * 8] =
                    bypass_load16(base + frag * 32 + sq * 8);
            }
        }
        __syncthreads();

        // ---- Phase A: x + prev2 partial gates (independent of h(t-1)) ----
        floatx4 acc[4];
        #pragma unroll
        for (int r = 0; r < 4; ++r) acc[r] = (floatx4){0.f, 0.f, 0.f, 0.f};
        {
            const short* xrow = (const short*)xs + ((size_t)t * 64 + bg * 16 + mrow) * 64 + quad * 8;
            short8 xa0 = *(const short8*)(xrow);
            short8 xa1 = *(const short8*)(xrow + 32);
            acc[0] = __builtin_amdgcn_mfma_f32_16x16x32_bf16(xa0, wf[0], acc[0], 0, 0, 0);
            acc[1] = __builtin_amdgcn_mfma_f32_16x16x32_bf16(xa1, wf[1], acc[1], 0, 0, 0);
            #pragma unroll
            for (int i = 0; i < 16; ++i) {
                short8 a = *(const short8*)&p2buf[mrow * LSTR + i * 32 + quad * 8];
                acc[(2 + i) & 3] = __builtin_amdgcn_mfma_f32_16x16x32_bf16(a, wf[2 + i], acc[(2 + i) & 3], 0, 0, 0);
            }
        }

        // ---- group barrier: wait until all 32 WGs completed step t-1 ----
        if (t) {
            if (tid == 0) {
                const unsigned tgt = 32u * (unsigned)t;
                while (__hip_atomic_load(ctr, __ATOMIC_RELAXED, __HIP_MEMORY_SCOPE_AGENT) < tgt) {}
            }
            __syncthreads();
        }

        // ---- stage h(t-1) into LDS ----
        {
            const short* base = (const short*)ring + ((size_t)((t + 31) & 63) * 64 + bg * 16 + sb) * 512;
            #pragma unroll
            for (int f = 0; f < 4; ++f) {
                int frag = w * 4 + f;
                *(short8*)&hbuf[sb * LSTR + frag * 32 + sq * 8] =
                    bypass_load16(base + frag * 32 + sq * 8);
            }
        }
        __syncthreads();

        // ---- Phase B: h(t-1) MFMAs ----
        #pragma unroll
        for (int i = 0; i < 16; ++i) {
            short8 a = *(const short8*)&hbuf[mrow * LSTR + i * 32 + quad * 8];
            acc[(18 + i) & 3] = __builtin_amdgcn_mfma_f32_16x16x32_bf16(a, wf[18 + i], acc[(18 + i) & 3], 0, 0, 0);
        }
        floatx4 s = acc[0] + acc[1] + acc[2] + acc[3];
        #pragma unroll
        for (int r = 0; r < 4; ++r) gsm[w][quad * 4 + r][mrow] = s[r] + bias_r;
        __syncthreads();

        // ---- LSTM cell: 128 threads x 2 cells; h store via bypass atomic ----
        if (tid < 128) {
            float gi0 = gsm[0][cm][2 * cj2],     gi1 = gsm[0][cm][2 * cj2 + 1];
            float gf0 = gsm[1][cm][2 * cj2],     gf1 = gsm[1][cm][2 * cj2 + 1];
            float gg0 = gsm[2][cm][2 * cj2],     gg1 = gsm[2][cm][2 * cj2 + 1];
            float go0 = gsm[3][cm][2 * cj2],     go1 = gsm[3][cm][2 * cj2 + 1];
            c0 = fsig(gf0) * c0 + fsig(gi0) * ftanh(gg0);
            c1 = fsig(gf1) * c1 + fsig(gi1) * ftanh(gg1);
            float h0 = fsig(go0) * ftanh(c0);
            float h1 = fsig(go1) * ftanh(c1);
            union { unsigned u; unsigned short sh[2]; } hp;
            union { bf16 b; unsigned short u; } cv;
            cv.b = __float2bfloat16(h0); hp.sh[0] = cv.u;
            cv.b = __float2bfloat16(h1); hp.sh[1] = cv.u;
            __hip_atomic_store(
                (unsigned*)((short*)ring + ((size_t)((t + 32) & 63) * 64 + gcb) * 512 + gn),
                hp.u, __ATOMIC_RELAXED, __HIP_MEMORY_SCOPE_AGENT);
            float2 o; o.x = h0; o.y = h1;
            *(float2*)(out + (size_t)gcb * TT * 512 + (size_t)t * 512 + gn) = o;   // (B,T,NC) flat
        }
        __syncthreads();   // drains all waves' vmcnt(0): h stores acked at coherence point

        if (tid == 0)
            __hip_atomic_fetch_add(ctr, 1u, __ATOMIC_RELAXED, __HIP_MEMORY_SCOPE_AGENT);
    }
}

extern "C" void kernel_launch(void* const* d_in, const int* in_sizes, int n_in,
                              void* d_out, int out_size, void* d_ws, size_t ws_size,
                              hipStream_t stream) {
    const float* batch = (const float*)d_in[0];
    const float* Wih   = (const float*)d_in[1];
    const float* Whh   = (const float*)d_in[2];
    const float* bih   = (const float*)d_in[3];
    const float* bhh   = (const float*)d_in[4];
    float* out = (float*)d_out;

    char* p = (char*)d_ws;
    bf16*  Wc     = (bf16*)p;     p += (size_t)2048 * KPAD * 2;          // 4,456,448
    float* bias   = (float*)p;    p += (size_t)2048 * 4;                 // 8,192
    bf16*  xs     = (bf16*)p;     p += (size_t)TT * 64 * 64 * 2;         // 8,388,608
    bf16*  ring   = (bf16*)p;     p += (size_t)64 * 64 * 512 * 2;        // 4,194,304
    unsigned* bar = (unsigned*)p; p += 512;                              // 4 groups x 128B

    // zero ring slots 0..31 (prev2 for t<32, h(-1) at slot 31) and barrier counters
    hipMemsetAsync(ring, 0, (size_t)32 * 64 * 512 * 2, stream);
    hipMemsetAsync(bar, 0, 512, stream);

    prep_wb<<<(2048 * KPAD + 255) / 256, 256, 0, stream>>>(Wih, Whh, bih, bhh, Wc, bias);
    prep_x<<<(TT * 64 * 64) / 256, 256, 0, stream>>>(batch, xs);

    lstm_persist<<<128, 256, 0, stream>>>(Wc, bias, xs, ring, out, bar);
}